// Round 2
// baseline (273.746 us; speedup 1.0000x reference)
//
#include <hip/hip_runtime.h>
#include <hip/hip_bf16.h>

// Problem constants (from reference)
#define B_   64
#define M_   256
#define D_   256
#define A_   18
#define E_   4
#define S_   64
#define ES_  256          // E_*S_ == M_
#define H_   512
#define K2_  (A_*D_)      // 4608

// ---------------------------------------------------------------------------
// Generic 64x64-tile fp32 GEMM body.  C[M x N] = act(op(A) * B + bias)
//   TA=false: A is [M][K], row-major, lda = row stride
//   TA=true : A is [K][M], row-major (k rows, m contiguous), lda = row stride
//   B is [K][N] row-major, ldb = row stride
// Block: 256 threads, 4x4 outputs/thread, BK=16.
// ---------------------------------------------------------------------------
template<bool TA, bool RELU, bool HAS_BIAS>
__device__ __forceinline__ void gemm_body(
    const float* __restrict__ A, int lda,
    const float* __restrict__ Bp, int ldb,
    const float* __restrict__ bias,
    float* __restrict__ C, int ldc, int K)
{
  __shared__ float As[16][68];   // [k][m], pad 68 keeps float4 reads aligned + conflict-light
  __shared__ float Bs[16][64];   // [k][n]
  const int t   = threadIdx.x;
  const int tx  = t & 15, ty = t >> 4;
  const int bm0 = blockIdx.y * 64, bn0 = blockIdx.x * 64;
  float acc[4][4] = {};

  for (int k0 = 0; k0 < K; k0 += 16) {
    if (TA) {
      // A tile is [16 k][64 m], m contiguous in memory -> direct float4 copy
      const int kr = t >> 4, mc = (t & 15) * 4;
      const float4 av = *reinterpret_cast<const float4*>(
          &A[(long)(k0 + kr) * lda + bm0 + mc]);
      *reinterpret_cast<float4*>(&As[kr][mc]) = av;
    } else {
      // A tile is [64 m][16 k]; transpose into As[k][m]
      const int ar = t >> 2, ac = (t & 3) * 4;
      const float4 av = *reinterpret_cast<const float4*>(
          &A[(long)(bm0 + ar) * lda + k0 + ac]);
      As[ac + 0][ar] = av.x; As[ac + 1][ar] = av.y;
      As[ac + 2][ar] = av.z; As[ac + 3][ar] = av.w;
    }
    {
      const int kr = t >> 4, nc = (t & 15) * 4;
      const float4 bv = *reinterpret_cast<const float4*>(
          &Bp[(long)(k0 + kr) * ldb + bn0 + nc]);
      *reinterpret_cast<float4*>(&Bs[kr][nc]) = bv;
    }
    __syncthreads();
#pragma unroll
    for (int k = 0; k < 16; ++k) {
      float a[4], b[4];
#pragma unroll
      for (int i = 0; i < 4; ++i) a[i] = As[k][ty * 4 + i];
#pragma unroll
      for (int j = 0; j < 4; ++j) b[j] = Bs[k][tx * 4 + j];
#pragma unroll
      for (int i = 0; i < 4; ++i)
#pragma unroll
        for (int j = 0; j < 4; ++j)
          acc[i][j] = fmaf(a[i], b[j], acc[i][j]);
    }
    __syncthreads();
  }

#pragma unroll
  for (int i = 0; i < 4; ++i) {
    const int row = bm0 + ty * 4 + i;
    const int col = bn0 + tx * 4;
    float4 v;
    v.x = acc[i][0]; v.y = acc[i][1]; v.z = acc[i][2]; v.w = acc[i][3];
    if (HAS_BIAS) {
      v.x += bias[col + 0]; v.y += bias[col + 1];
      v.z += bias[col + 2]; v.w += bias[col + 3];
    }
    if (RELU) {
      v.x = fmaxf(v.x, 0.f); v.y = fmaxf(v.y, 0.f);
      v.z = fmaxf(v.z, 0.f); v.w = fmaxf(v.w, 0.f);
    }
    *reinterpret_cast<float4*>(&C[(long)row * ldc + col]) = v;
  }
}

// ---- step 1: logits[b][m][es] = obs[b] @ phi ------------------------------
__global__ __launch_bounds__(256) void k_logits(
    const float* __restrict__ obs, const float* __restrict__ phi,
    float* __restrict__ out)
{
  const int b = blockIdx.z;
  gemm_body<false, false, false>(obs + (long)b * M_ * D_, D_,
                                 phi, ES_, nullptr,
                                 out + (long)b * M_ * ES_, ES_, D_);
}

// ---- step 2a: dispatch = softmax over tokens m (column softmax) -----------
__global__ __launch_bounds__(256) void k_dispatch(
    const float* __restrict__ logits, float* __restrict__ dispatch)
{
  // grid: (ES_/64, B_); block 256 = 64 es-lanes x 4 m-groups
  const int t  = threadIdx.x;
  const int x  = t & 63;
  const int g  = t >> 6;
  const int es0 = blockIdx.x * 64;
  const long base = (long)blockIdx.y * (M_ * ES_) + es0 + x;

  float mx = -1e30f, sm = 0.f;
  for (int m = g; m < M_; m += 4) {
    const float v  = logits[base + (long)m * ES_];
    const float nm = fmaxf(mx, v);
    sm = sm * __expf(mx - nm) + __expf(v - nm);
    mx = nm;
  }
  __shared__ float smx[4][64], ssm[4][64];
  smx[g][x] = mx; ssm[g][x] = sm;
  __syncthreads();
  if (g == 0) {
    float M0 = smx[0][x], S0 = ssm[0][x];
#pragma unroll
    for (int i = 1; i < 4; ++i) {
      const float Mi = smx[i][x], Si = ssm[i][x];
      const float nm = fmaxf(M0, Mi);
      S0 = S0 * __expf(M0 - nm) + Si * __expf(Mi - nm);
      M0 = nm;
    }
    smx[0][x] = M0; ssm[0][x] = 1.0f / S0;
  }
  __syncthreads();
  const float M0 = smx[0][x], inv = ssm[0][x];
  for (int m = g; m < M_; m += 4) {
    const float v = logits[base + (long)m * ES_];
    dispatch[base + (long)m * ES_] = __expf(v - M0) * inv;
  }
}

// ---- step 2b: combine = softmax over all ES slots (row softmax, in-place) -
__global__ __launch_bounds__(256) void k_combine(float* __restrict__ logits)
{
  // grid: B_*M_/4 blocks; one 64-lane wave per row of 256 floats
  const int t    = threadIdx.x;
  const int lane = t & 63;
  const int wv   = t >> 6;
  const long row = (long)blockIdx.x * 4 + wv;
  float4 v = *reinterpret_cast<float4*>(&logits[row * ES_ + lane * 4]);
  float mx = fmaxf(fmaxf(v.x, v.y), fmaxf(v.z, v.w));
#pragma unroll
  for (int o = 32; o; o >>= 1) mx = fmaxf(mx, __shfl_xor(mx, o));
  const float e0 = __expf(v.x - mx), e1 = __expf(v.y - mx);
  const float e2 = __expf(v.z - mx), e3 = __expf(v.w - mx);
  float sm = e0 + e1 + e2 + e3;
#pragma unroll
  for (int o = 32; o; o >>= 1) sm += __shfl_xor(sm, o);
  const float inv = 1.0f / sm;
  float4 r; r.x = e0 * inv; r.y = e1 * inv; r.z = e2 * inv; r.w = e3 * inv;
  *reinterpret_cast<float4*>(&logits[row * ES_ + lane * 4]) = r;
}

// ---- step 3: slots[b][es][d] = dispatch[b]^T @ obs[b] ---------------------
__global__ __launch_bounds__(256) void k_slots(
    const float* __restrict__ dispatch, const float* __restrict__ obs,
    float* __restrict__ slots)
{
  const int b = blockIdx.z;
  gemm_body<true, false, false>(dispatch + (long)b * M_ * ES_, ES_,
                                obs + (long)b * M_ * D_, D_, nullptr,
                                slots + (long)b * ES_ * D_, D_, M_);
}

// ---- step 4: h[b][e][s][j] = relu(slots @ w1[e] + b1[e]) ------------------
__global__ __launch_bounds__(256) void k_h(
    const float* __restrict__ slots, const float* __restrict__ w1,
    const float* __restrict__ b1, float* __restrict__ h)
{
  const int z = blockIdx.z; const int b = z >> 2, e = z & 3;
  gemm_body<false, true, true>(slots + (long)b * ES_ * D_ + (long)e * S_ * D_, D_,
                               w1 + (long)e * D_ * H_, H_,
                               b1 + (long)e * H_,
                               h + (long)z * S_ * H_, H_, D_);
}

// ---- step 5: y_sel[b][es][d] = h @ w2[e][:, a*D : a*D+D] + b2 slice -------
// action is int32 on device (harness materializes integer inputs as int32).
__global__ __launch_bounds__(256) void k_y(
    const float* __restrict__ h, const float* __restrict__ w2,
    const float* __restrict__ b2, const int* __restrict__ action,
    float* __restrict__ y)
{
  const int z = blockIdx.z; const int b = z >> 2, e = z & 3;
  int a = action[b];
  a = (a < 0) ? 0 : (a >= A_ ? A_ - 1 : a);   // defensive clamp
  gemm_body<false, false, true>(h + (long)z * S_ * H_, H_,
                                w2 + (long)e * H_ * K2_ + (long)a * D_, K2_,
                                b2 + (long)e * K2_ + (long)a * D_,
                                y + (long)b * ES_ * D_ + (long)e * S_ * D_, D_, H_);
}

// ---- step 6: out[b][m][d] = combine[b] @ y_sel[b] -------------------------
__global__ __launch_bounds__(256) void k_out(
    const float* __restrict__ combine, const float* __restrict__ y,
    float* __restrict__ out)
{
  const int b = blockIdx.z;
  gemm_body<false, false, false>(combine + (long)b * M_ * ES_, ES_,
                                 y + (long)b * ES_ * D_, D_, nullptr,
                                 out + (long)b * M_ * D_, D_, ES_);
}

// ---------------------------------------------------------------------------
extern "C" void kernel_launch(void* const* d_in, const int* in_sizes, int n_in,
                              void* d_out, int out_size, void* d_ws, size_t ws_size,
                              hipStream_t stream)
{
  const float* obs    = (const float*)d_in[0];
  const int*   action = (const int*)d_in[1];   // harness: integer -> int32
  const float* phi    = (const float*)d_in[2];
  const float* w1     = (const float*)d_in[3];
  const float* b1     = (const float*)d_in[4];
  const float* w2     = (const float*)d_in[5];
  const float* b2     = (const float*)d_in[6];
  float*       out    = (float*)d_out;

  // Workspace layout (floats). Total = 20,971,520 floats = 80 MB.
  //   [0]          logits  -> overwritten in-place by combine
  //   [4194304]    dispatch -> reused for y_sel after slots are built
  //   [8388608]    slots
  //   [12582912]   h (8,388,608 floats)
  float* ws       = (float*)d_ws;
  float* logits   = ws;
  float* dispatch = ws + 4194304;
  float* slots    = ws + 2 * 4194304;
  float* hbuf     = ws + 3 * 4194304;
  float* ybuf     = dispatch;   // dispatch is dead after k_slots

  k_logits  <<<dim3(4, 4, 64),  256, 0, stream>>>(obs, phi, logits);
  k_dispatch<<<dim3(4, 64),     256, 0, stream>>>(logits, dispatch);
  k_combine <<<dim3(4096),      256, 0, stream>>>(logits);              // in-place
  k_slots   <<<dim3(4, 4, 64),  256, 0, stream>>>(dispatch, obs, slots);
  k_h       <<<dim3(8, 1, 256), 256, 0, stream>>>(slots, w1, b1, hbuf);
  k_y       <<<dim3(4, 1, 256), 256, 0, stream>>>(hbuf, w2, b2, action, ybuf);
  k_out     <<<dim3(4, 4, 64),  256, 0, stream>>>(logits /*=combine*/, ybuf, out);
}

// Round 3
// 186.201 us; speedup vs baseline: 1.4702x; 1.4702x over previous
//
#include <hip/hip_runtime.h>

// Problem constants
#define B_   64
#define M_   256
#define D_   256
#define A_   18
#define E_   4
#define S_   64
#define ES_  256          // E_*S_ == M_
#define H_   512
#define K2_  (A_*D_)      // 4608

typedef _Float16 f16;
typedef _Float16 f16x4 __attribute__((ext_vector_type(4)));
typedef _Float16 f16x8 __attribute__((ext_vector_type(8)));
typedef float    f32x4 __attribute__((ext_vector_type(4)));

// ===========================================================================
// Conversion / transpose kernels (one-time per call)
// ===========================================================================

// fp32 src [z][R][C] -> fp16 dst [z][C][R]  (transpose + convert)
__global__ __launch_bounds__(256) void k_tcvt(
    const float* __restrict__ src, f16* __restrict__ dst,
    int R, int C, long sbs, long dbs)
{
  __shared__ f16 T[64][68];
  const int t = threadIdx.x;
  const int rr = t >> 4, cc = (t & 15) * 4;
  const int r0 = blockIdx.y * 64, c0 = blockIdx.x * 64;
  src += (long)blockIdx.z * sbs;
  dst += (long)blockIdx.z * dbs;
#pragma unroll
  for (int p = 0; p < 4; ++p) {
    const int row = rr + p * 16;
    const float4 v = *reinterpret_cast<const float4*>(
        &src[(long)(r0 + row) * C + c0 + cc]);
    T[row][cc + 0] = (f16)v.x; T[row][cc + 1] = (f16)v.y;
    T[row][cc + 2] = (f16)v.z; T[row][cc + 3] = (f16)v.w;
  }
  __syncthreads();
#pragma unroll
  for (int p = 0; p < 4; ++p) {
    const int oc = rr + p * 16;          // src-col index = dst row
    f16x4 g;
#pragma unroll
    for (int i = 0; i < 4; ++i) g[i] = T[cc + i][oc];
    *reinterpret_cast<f16x4*>(&dst[(long)(c0 + oc) * R + r0 + cc]) = g;
  }
}

// obs fp32 [b][M][D] -> obs16 [b][M][D] and obsT16 [b][D][M]
__global__ __launch_bounds__(256) void k_cvt_obs(
    const float* __restrict__ obs, f16* __restrict__ o16, f16* __restrict__ oT)
{
  __shared__ f16 T[64][68];
  const int t = threadIdx.x, rr = t >> 4, cc = (t & 15) * 4;
  const int r0 = blockIdx.y * 64, c0 = blockIdx.x * 64;
  const long bo = (long)blockIdx.z * (M_ * D_);
#pragma unroll
  for (int p = 0; p < 4; ++p) {
    const int row = rr + p * 16;
    const float4 v = *reinterpret_cast<const float4*>(
        &obs[bo + (long)(r0 + row) * D_ + c0 + cc]);
    f16x4 h; h[0] = (f16)v.x; h[1] = (f16)v.y; h[2] = (f16)v.z; h[3] = (f16)v.w;
    *reinterpret_cast<f16x4*>(&o16[bo + (long)(r0 + row) * D_ + c0 + cc]) = h;
    T[row][cc + 0] = h[0]; T[row][cc + 1] = h[1];
    T[row][cc + 2] = h[2]; T[row][cc + 3] = h[3];
  }
  __syncthreads();
#pragma unroll
  for (int p = 0; p < 4; ++p) {
    const int oc = rr + p * 16;
    f16x4 g;
#pragma unroll
    for (int i = 0; i < 4; ++i) g[i] = T[cc + i][oc];
    *reinterpret_cast<f16x4*>(&oT[bo + (long)(c0 + oc) * M_ + r0 + cc]) = g;
  }
}

// fp16 [z][256][256] transpose
__global__ __launch_bounds__(256) void k_t16(
    const f16* __restrict__ src, f16* __restrict__ dst)
{
  __shared__ f16 T[64][68];
  const int t = threadIdx.x, rr = t >> 4, cc = (t & 15) * 4;
  const int r0 = blockIdx.y * 64, c0 = blockIdx.x * 64;
  const long bo = (long)blockIdx.z * (256 * 256);
#pragma unroll
  for (int p = 0; p < 4; ++p) {
    const int row = rr + p * 16;
    const f16x4 v = *reinterpret_cast<const f16x4*>(
        &src[bo + (long)(r0 + row) * 256 + c0 + cc]);
    T[row][cc + 0] = v[0]; T[row][cc + 1] = v[1];
    T[row][cc + 2] = v[2]; T[row][cc + 3] = v[3];
  }
  __syncthreads();
#pragma unroll
  for (int p = 0; p < 4; ++p) {
    const int oc = rr + p * 16;
    f16x4 g;
#pragma unroll
    for (int i = 0; i < 4; ++i) g[i] = T[cc + i][oc];
    *reinterpret_cast<f16x4*>(&dst[bo + (long)(c0 + oc) * 256 + r0 + cc]) = g;
  }
}

// ===========================================================================
// MFMA GEMM core: C[64x64 tile] = act(A[M][K] * BT[N][K]^T + bias)
// 256 threads = 4 waves; wave (wr,wc) owns a 32x32 quadrant (2x2 frags).
// A, BT fp16 K-contiguous; direct global->register fragment loads.
// OUT_MODE: 0 = fp16 normal [M][N], 1 = fp16 transposed [N][M], 2 = fp32 [M][N]
// ===========================================================================
template<int RELU, int HAS_BIAS, int OUT_MODE>
__device__ __forceinline__ void mfma_gemm(
    const f16* __restrict__ A, int lda,
    const f16* __restrict__ BT, int ldb,
    const float* __restrict__ bias,
    void* __restrict__ Cout, int ldc, int K)
{
  const int t    = threadIdx.x;
  const int w    = t >> 6, lane = t & 63;
  const int wr   = w >> 1, wc = w & 1;
  const int m0   = blockIdx.y * 64 + wr * 32;
  const int n0   = blockIdx.x * 64 + wc * 32;
  const int lr   = lane & 15;
  const int lk   = (lane >> 4) * 8;       // k-offset within 32-wide step

  f32x4 acc00 = {}, acc01 = {}, acc10 = {}, acc11 = {};
  const f16* Ap = A  + (long)(m0 + lr) * lda + lk;
  const f16* Bp = BT + (long)(n0 + lr) * ldb + lk;

  for (int k0 = 0; k0 < K; k0 += 32) {
    const f16x8 a0 = *reinterpret_cast<const f16x8*>(Ap);
    const f16x8 a1 = *reinterpret_cast<const f16x8*>(Ap + (long)16 * lda);
    const f16x8 b0 = *reinterpret_cast<const f16x8*>(Bp);
    const f16x8 b1 = *reinterpret_cast<const f16x8*>(Bp + (long)16 * ldb);
    acc00 = __builtin_amdgcn_mfma_f32_16x16x32_f16(a0, b0, acc00, 0, 0, 0);
    acc01 = __builtin_amdgcn_mfma_f32_16x16x32_f16(a0, b1, acc01, 0, 0, 0);
    acc10 = __builtin_amdgcn_mfma_f32_16x16x32_f16(a1, b0, acc10, 0, 0, 0);
    acc11 = __builtin_amdgcn_mfma_f32_16x16x32_f16(a1, b1, acc11, 0, 0, 0);
    Ap += 32; Bp += 32;
  }

  // epilogue: D[row = 4*(lane>>4)+r][col = lane&15] per 16x16 fragment
  const int orow = (lane >> 4) * 4;
  f32x4 accs[2][2] = {{acc00, acc01}, {acc10, acc11}};
#pragma unroll
  for (int fi = 0; fi < 2; ++fi) {
#pragma unroll
    for (int fj = 0; fj < 2; ++fj) {
      const int gm = m0 + fi * 16 + orow;
      const int gn = n0 + fj * 16 + lr;
      f32x4 v = accs[fi][fj];
      if (HAS_BIAS) {
        const float bv = bias[gn];
        v[0] += bv; v[1] += bv; v[2] += bv; v[3] += bv;
      }
      if (RELU) {
#pragma unroll
        for (int r = 0; r < 4; ++r) v[r] = fmaxf(v[r], 0.f);
      }
      if (OUT_MODE == 0) {
        f16* C = (f16*)Cout;
#pragma unroll
        for (int r = 0; r < 4; ++r) C[(long)(gm + r) * ldc + gn] = (f16)v[r];
      } else if (OUT_MODE == 1) {
        f16x4 h; h[0] = (f16)v[0]; h[1] = (f16)v[1];
        h[2] = (f16)v[2]; h[3] = (f16)v[3];
        *reinterpret_cast<f16x4*>(&((f16*)Cout)[(long)gn * ldc + gm]) = h;
      } else {
        float* C = (float*)Cout;
#pragma unroll
        for (int r = 0; r < 4; ++r) C[(long)(gm + r) * ldc + gn] = v[r];
      }
    }
  }
}

// ---- GEMM kernel wrappers -------------------------------------------------

// logits16[b][m][es] = obs16[b] @ phiT^T
__global__ __launch_bounds__(256) void k_logits(
    const f16* __restrict__ obs16, const f16* __restrict__ phiT,
    f16* __restrict__ logits16)
{
  const long b = blockIdx.z;
  mfma_gemm<0, 0, 0>(obs16 + b * (M_ * D_), D_, phiT, D_, nullptr,
                     logits16 + b * (M_ * ES_), ES_, D_);
}

// slots16[b][es][d] = dispT16[b] @ obsT16[b]^T   (K = m)
__global__ __launch_bounds__(256) void k_slots(
    const f16* __restrict__ dispT, const f16* __restrict__ obsT,
    f16* __restrict__ slots16)
{
  const long b = blockIdx.z;
  mfma_gemm<0, 0, 0>(dispT + b * (ES_ * M_), M_, obsT + b * (D_ * M_), M_,
                     nullptr, slots16 + b * (ES_ * D_), D_, M_);
}

// h16[z][s][h] = relu(slots16[b,e] @ w1T[e]^T + b1[e])
__global__ __launch_bounds__(256) void k_h(
    const f16* __restrict__ slots16, const f16* __restrict__ w1T,
    const float* __restrict__ b1, f16* __restrict__ h16)
{
  const long z = blockIdx.z; const long e = z & 3;
  mfma_gemm<1, 1, 0>(slots16 + z * (S_ * D_), D_,
                     w1T + e * (H_ * D_), D_,
                     b1 + e * H_,
                     h16 + z * (S_ * H_), H_, D_);
}

// yT16[b][d][es] (transposed write) = h16[b,e] @ w2T[e, a*D: ]^T + b2 slice
__global__ __launch_bounds__(256) void k_y(
    const f16* __restrict__ h16, const f16* __restrict__ w2T,
    const float* __restrict__ b2, const int* __restrict__ action,
    f16* __restrict__ yT16)
{
  const long z = blockIdx.z; const long b = z >> 2, e = z & 3;
  int a = action[b];
  a = (a < 0) ? 0 : (a >= A_ ? A_ - 1 : a);
  mfma_gemm<0, 1, 1>(h16 + z * (S_ * H_), H_,
                     w2T + e * ((long)K2_ * H_) + (long)a * D_ * H_, H_,
                     b2 + e * K2_ + a * D_,
                     yT16 + b * (D_ * ES_) + e * S_, ES_, H_);
}

// out[b][m][d] (fp32) = comb16[b] @ yT16[b]^T   (K = es)
__global__ __launch_bounds__(256) void k_out(
    const f16* __restrict__ comb16, const f16* __restrict__ yT16,
    float* __restrict__ out)
{
  const long b = blockIdx.z;
  mfma_gemm<0, 0, 2>(comb16 + b * (M_ * ES_), ES_, yT16 + b * (D_ * ES_), ES_,
                     nullptr, out + b * (M_ * D_), D_, ES_);
}

// ===========================================================================
// Softmax kernels (fp16 in / fp16 out, fp32 math)
// ===========================================================================

// dispatch: softmax over tokens m (columns of logits16[b])
__global__ __launch_bounds__(256) void k_dispatch(
    const f16* __restrict__ logits16, f16* __restrict__ disp16)
{
  const int t = threadIdx.x;
  const int x = t & 63, g = t >> 6;
  const int es0 = blockIdx.x * 64;
  const long base = (long)blockIdx.y * (M_ * ES_) + es0 + x;

  float mx = -1e30f, sm = 0.f;
  for (int m = g; m < M_; m += 4) {
    const float v  = (float)logits16[base + (long)m * ES_];
    const float nm = fmaxf(mx, v);
    sm = sm * __expf(mx - nm) + __expf(v - nm);
    mx = nm;
  }
  __shared__ float smx[4][64], ssm[4][64];
  smx[g][x] = mx; ssm[g][x] = sm;
  __syncthreads();
  if (g == 0) {
    float M0 = smx[0][x], S0 = ssm[0][x];
#pragma unroll
    for (int i = 1; i < 4; ++i) {
      const float Mi = smx[i][x], Si = ssm[i][x];
      const float nm = fmaxf(M0, Mi);
      S0 = S0 * __expf(M0 - nm) + Si * __expf(Mi - nm);
      M0 = nm;
    }
    smx[0][x] = M0; ssm[0][x] = 1.0f / S0;
  }
  __syncthreads();
  const float M0 = smx[0][x], inv = ssm[0][x];
  for (int m = g; m < M_; m += 4) {
    const float v = (float)logits16[base + (long)m * ES_];
    disp16[base + (long)m * ES_] = (f16)(__expf(v - M0) * inv);
  }
}

// combine: softmax over all ES slots per (b,m) row
__global__ __launch_bounds__(256) void k_combine(
    const f16* __restrict__ logits16, f16* __restrict__ comb16)
{
  const int t = threadIdx.x;
  const int lane = t & 63, wv = t >> 6;
  const long row = (long)blockIdx.x * 4 + wv;
  const f16x4 v = *reinterpret_cast<const f16x4*>(&logits16[row * ES_ + lane * 4]);
  float f0 = (float)v[0], f1 = (float)v[1], f2 = (float)v[2], f3 = (float)v[3];
  float mx = fmaxf(fmaxf(f0, f1), fmaxf(f2, f3));
#pragma unroll
  for (int o = 32; o; o >>= 1) mx = fmaxf(mx, __shfl_xor(mx, o));
  const float e0 = __expf(f0 - mx), e1 = __expf(f1 - mx);
  const float e2 = __expf(f2 - mx), e3 = __expf(f3 - mx);
  float sm = e0 + e1 + e2 + e3;
#pragma unroll
  for (int o = 32; o; o >>= 1) sm += __shfl_xor(sm, o);
  const float inv = 1.0f / sm;
  f16x4 r; r[0] = (f16)(e0 * inv); r[1] = (f16)(e1 * inv);
  r[2] = (f16)(e2 * inv); r[3] = (f16)(e3 * inv);
  *reinterpret_cast<f16x4*>(&comb16[row * ES_ + lane * 4]) = r;
}

// ===========================================================================
extern "C" void kernel_launch(void* const* d_in, const int* in_sizes, int n_in,
                              void* d_out, int out_size, void* d_ws, size_t ws_size,
                              hipStream_t stream)
{
  const float* obs    = (const float*)d_in[0];
  const int*   action = (const int*)d_in[1];
  const float* phi    = (const float*)d_in[2];
  const float* w1     = (const float*)d_in[3];
  const float* b1     = (const float*)d_in[4];
  const float* w2     = (const float*)d_in[5];
  const float* b2     = (const float*)d_in[6];
  float*       out    = (float*)d_out;

  // Workspace layout in fp16 units (~65 MB total, aliased):
  f16* ws = (f16*)d_ws;
  f16* obs16   = ws + 0;          // 4,194,304      -> later disp16, then h16 lo
  f16* obsT16  = ws + 4194304;    // 4,194,304      -> later h16 hi
  f16* phiT    = ws + 8388608;    //    65,536
  f16* w1T     = ws + 8454144;    // 2,097,152
  f16* w2T     = ws + 10551296;   // 9,437,184
  f16* logits16= ws + 19988480;   // 4,194,304      -> later dispT16
  f16* comb16  = ws + 24182784;   // 4,194,304
  f16* slots16 = ws + 28377088;   // 4,194,304      -> later yT16
  f16* disp16  = obs16;           // alias (obs16 dead after k_logits)
  f16* dispT16 = logits16;        // alias (logits dead after k_combine)
  f16* h16     = obs16;           // alias, 8,388,608 halves (spans obs16+obsT16)
  f16* yT16    = slots16;         // alias (slots dead after k_h)

  // --- one-time conversions ---
  k_cvt_obs<<<dim3(4, 4, 64), 256, 0, stream>>>(obs, obs16, obsT16);
  k_tcvt   <<<dim3(4, 4, 1),  256, 0, stream>>>(phi, phiT, 256, 256, 0, 0);
  k_tcvt   <<<dim3(8, 4, 4),  256, 0, stream>>>(w1, w1T, D_, H_,
                                                (long)D_ * H_, (long)H_ * D_);
  k_tcvt   <<<dim3(72, 8, 4), 256, 0, stream>>>(w2, w2T, H_, K2_,
                                                (long)H_ * K2_, (long)K2_ * H_);
  // --- pipeline ---
  k_logits  <<<dim3(4, 4, 64), 256, 0, stream>>>(obs16, phiT, logits16);
  k_dispatch<<<dim3(4, 64),    256, 0, stream>>>(logits16, disp16);
  k_combine <<<dim3(4096),     256, 0, stream>>>(logits16, comb16);
  k_t16     <<<dim3(4, 4, 64), 256, 0, stream>>>(disp16, dispT16);
  k_slots   <<<dim3(4, 4, 64), 256, 0, stream>>>(dispT16, obsT16, slots16);
  k_h       <<<dim3(8, 1, 256),256, 0, stream>>>(slots16, w1T, b1, h16);
  k_y       <<<dim3(4, 1, 256),256, 0, stream>>>(h16, w2T, b2, action, yT16);
  k_out     <<<dim3(4, 4, 64), 256, 0, stream>>>(comb16, yT16, out);
}

// Round 4
// 140.377 us; speedup vs baseline: 1.9501x; 1.3264x over previous
//
#include <hip/hip_runtime.h>

// Problem constants
#define B_   64
#define M_   256
#define D_   256
#define A_   18
#define E_   4
#define S_   64
#define ES_  256          // E_*S_ == M_
#define H_   512
#define K2_  (A_*D_)      // 4608

typedef _Float16 f16;
typedef _Float16 f16x4 __attribute__((ext_vector_type(4)));
typedef _Float16 f16x8 __attribute__((ext_vector_type(8)));
typedef float    f32x4 __attribute__((ext_vector_type(4)));

// ===========================================================================
// Conversion / transpose kernels (one-time per call)
// ===========================================================================

// fp32 src [z][R][C] -> fp16 dst [z][C][R]  (transpose + convert)
__global__ __launch_bounds__(256) void k_tcvt(
    const float* __restrict__ src, f16* __restrict__ dst,
    int R, int C, long sbs, long dbs)
{
  __shared__ f16 T[64][68];
  const int t = threadIdx.x;
  const int rr = t >> 4, cc = (t & 15) * 4;
  const int r0 = blockIdx.y * 64, c0 = blockIdx.x * 64;
  src += (long)blockIdx.z * sbs;
  dst += (long)blockIdx.z * dbs;
#pragma unroll
  for (int p = 0; p < 4; ++p) {
    const int row = rr + p * 16;
    const float4 v = *reinterpret_cast<const float4*>(
        &src[(long)(r0 + row) * C + c0 + cc]);
    T[row][cc + 0] = (f16)v.x; T[row][cc + 1] = (f16)v.y;
    T[row][cc + 2] = (f16)v.z; T[row][cc + 3] = (f16)v.w;
  }
  __syncthreads();
#pragma unroll
  for (int p = 0; p < 4; ++p) {
    const int oc = rr + p * 16;          // src-col index = dst row
    f16x4 g;
#pragma unroll
    for (int i = 0; i < 4; ++i) g[i] = T[cc + i][oc];
    *reinterpret_cast<f16x4*>(&dst[(long)(c0 + oc) * R + r0 + cc]) = g;
  }
}

// obs fp32 [b][M][D] -> obs16 [b][M][D] and obsT16 [b][D][M]
__global__ __launch_bounds__(256) void k_cvt_obs(
    const float* __restrict__ obs, f16* __restrict__ o16, f16* __restrict__ oT)
{
  __shared__ f16 T[64][68];
  const int t = threadIdx.x, rr = t >> 4, cc = (t & 15) * 4;
  const int r0 = blockIdx.y * 64, c0 = blockIdx.x * 64;
  const long bo = (long)blockIdx.z * (M_ * D_);
#pragma unroll
  for (int p = 0; p < 4; ++p) {
    const int row = rr + p * 16;
    const float4 v = *reinterpret_cast<const float4*>(
        &obs[bo + (long)(r0 + row) * D_ + c0 + cc]);
    f16x4 h; h[0] = (f16)v.x; h[1] = (f16)v.y; h[2] = (f16)v.z; h[3] = (f16)v.w;
    *reinterpret_cast<f16x4*>(&o16[bo + (long)(r0 + row) * D_ + c0 + cc]) = h;
    T[row][cc + 0] = h[0]; T[row][cc + 1] = h[1];
    T[row][cc + 2] = h[2]; T[row][cc + 3] = h[3];
  }
  __syncthreads();
#pragma unroll
  for (int p = 0; p < 4; ++p) {
    const int oc = rr + p * 16;
    f16x4 g;
#pragma unroll
    for (int i = 0; i < 4; ++i) g[i] = T[cc + i][oc];
    *reinterpret_cast<f16x4*>(&oT[bo + (long)(c0 + oc) * M_ + r0 + cc]) = g;
  }
}

// ===========================================================================
// MFMA GEMM core: C[64x64 tile] = act(A[M][K] * BT[N][K]^T + bias)
// 256 threads = 4 waves; wave (wr,wc) owns a 32x32 quadrant (2x2 frags).
// OUT_MODE: 0 = fp16 normal [M][N], 2 = fp32 [M][N]
// ===========================================================================
template<int OUT_MODE>
__device__ __forceinline__ void mfma_gemm(
    const f16* __restrict__ A, int lda,
    const f16* __restrict__ BT, int ldb,
    void* __restrict__ Cout, int ldc, int K)
{
  const int t    = threadIdx.x;
  const int w    = t >> 6, lane = t & 63;
  const int wr   = w >> 1, wc = w & 1;
  const int m0   = blockIdx.y * 64 + wr * 32;
  const int n0   = blockIdx.x * 64 + wc * 32;
  const int lr   = lane & 15;
  const int lk   = (lane >> 4) * 8;       // k-offset within 32-wide step

  f32x4 acc00 = {}, acc01 = {}, acc10 = {}, acc11 = {};
  const f16* Ap = A  + (long)(m0 + lr) * lda + lk;
  const f16* Bp = BT + (long)(n0 + lr) * ldb + lk;

  for (int k0 = 0; k0 < K; k0 += 32) {
    const f16x8 a0 = *reinterpret_cast<const f16x8*>(Ap);
    const f16x8 a1 = *reinterpret_cast<const f16x8*>(Ap + (long)16 * lda);
    const f16x8 b0 = *reinterpret_cast<const f16x8*>(Bp);
    const f16x8 b1 = *reinterpret_cast<const f16x8*>(Bp + (long)16 * ldb);
    acc00 = __builtin_amdgcn_mfma_f32_16x16x32_f16(a0, b0, acc00, 0, 0, 0);
    acc01 = __builtin_amdgcn_mfma_f32_16x16x32_f16(a0, b1, acc01, 0, 0, 0);
    acc10 = __builtin_amdgcn_mfma_f32_16x16x32_f16(a1, b0, acc10, 0, 0, 0);
    acc11 = __builtin_amdgcn_mfma_f32_16x16x32_f16(a1, b1, acc11, 0, 0, 0);
    Ap += 32; Bp += 32;
  }

  const int orow = (lane >> 4) * 4;
  f32x4 accs[2][2] = {{acc00, acc01}, {acc10, acc11}};
#pragma unroll
  for (int fi = 0; fi < 2; ++fi) {
#pragma unroll
    for (int fj = 0; fj < 2; ++fj) {
      const int gm = m0 + fi * 16 + orow;
      const int gn = n0 + fj * 16 + lr;
      f32x4 v = accs[fi][fj];
      if (OUT_MODE == 0) {
        f16* C = (f16*)Cout;
#pragma unroll
        for (int r = 0; r < 4; ++r) C[(long)(gm + r) * ldc + gn] = (f16)v[r];
      } else {
        float* C = (float*)Cout;
#pragma unroll
        for (int r = 0; r < 4; ++r) C[(long)(gm + r) * ldc + gn] = v[r];
      }
    }
  }
}

// logits16[b][m][es] = obs16[b] @ phiT^T
__global__ __launch_bounds__(256) void k_logits(
    const f16* __restrict__ obs16, const f16* __restrict__ phiT,
    f16* __restrict__ logits16)
{
  const long b = blockIdx.z;
  mfma_gemm<0>(obs16 + b * (M_ * D_), D_, phiT, D_,
               logits16 + b * (M_ * ES_), ES_, D_);
}

// slots16[b][es][d] = dispT16[b] @ obsT16[b]^T   (K = m)
__global__ __launch_bounds__(256) void k_slots(
    const f16* __restrict__ dispT, const f16* __restrict__ obsT,
    f16* __restrict__ slots16)
{
  const long b = blockIdx.z;
  mfma_gemm<0>(dispT + b * (ES_ * M_), M_, obsT + b * (D_ * M_), M_,
               slots16 + b * (ES_ * D_), D_, M_);
}

// out[b][m][d] (fp32) = comb16[b] @ yT16[b]^T   (K = es)
__global__ __launch_bounds__(256) void k_out(
    const f16* __restrict__ comb16, const f16* __restrict__ yT16,
    float* __restrict__ out)
{
  const long b = blockIdx.z;
  mfma_gemm<2>(comb16 + b * (M_ * ES_), ES_, yT16 + b * (D_ * ES_), ES_,
               out + b * (M_ * D_), D_, ES_);
}

// ===========================================================================
// dispatch softmax over tokens m + transposed write: dispT[b][es][m]
// grid (ES_/64, B_), 256 threads
// ===========================================================================
__global__ __launch_bounds__(256) void k_dispatchT(
    const f16* __restrict__ logits16, f16* __restrict__ dispT16)
{
  const int t = threadIdx.x;
  const int x = t & 63, g = t >> 6;
  const int es0 = blockIdx.x * 64;
  const long bbase = (long)blockIdx.y * (M_ * ES_);

  // phase 1: column stats (max, sum) for es0 + x
  float mx = -1e30f, sm = 0.f;
  for (int m = g; m < M_; m += 4) {
    const float v  = (float)logits16[bbase + (long)m * ES_ + es0 + x];
    const float nm = fmaxf(mx, v);
    sm = sm * __expf(mx - nm) + __expf(v - nm);
    mx = nm;
  }
  __shared__ float smx[4][64], ssm[4][64];
  __shared__ float cmax[64], cinv[64];
  smx[g][x] = mx; ssm[g][x] = sm;
  __syncthreads();
  if (t < 64) {
    float M0 = smx[0][t], S0 = ssm[0][t];
#pragma unroll
    for (int i = 1; i < 4; ++i) {
      const float Mi = smx[i][t], Si = ssm[i][t];
      const float nm = fmaxf(M0, Mi);
      S0 = S0 * __expf(M0 - nm) + Si * __expf(Mi - nm);
      M0 = nm;
    }
    cmax[t] = M0; cinv[t] = 1.0f / S0;
  }
  __syncthreads();

  // phase 2: tile-wise exp + transpose through LDS, coalesced write
  __shared__ f16 T[64][68];
  const int rr = t >> 4, cc4 = (t & 15) * 4;
  for (int m0 = 0; m0 < M_; m0 += 64) {
#pragma unroll
    for (int p = 0; p < 4; ++p) {
      const int mr = rr + p * 16;
      const f16x4 v = *reinterpret_cast<const f16x4*>(
          &logits16[bbase + (long)(m0 + mr) * ES_ + es0 + cc4]);
#pragma unroll
      for (int i = 0; i < 4; ++i) {
        const int es = cc4 + i;
        T[es][mr] = (f16)(__expf((float)v[i] - cmax[es]) * cinv[es]);
      }
    }
    __syncthreads();
#pragma unroll
    for (int p = 0; p < 4; ++p) {
      const int er = rr + p * 16;
      const f16x4 gv = *reinterpret_cast<const f16x4*>(&T[er][cc4]);
      *reinterpret_cast<f16x4*>(
          &dispT16[bbase + (long)(es0 + er) * M_ + m0 + cc4]) = gv;
    }
    __syncthreads();
  }
}

// combine: softmax over all ES slots per (b,m) row
__global__ __launch_bounds__(256) void k_combine(
    const f16* __restrict__ logits16, f16* __restrict__ comb16)
{
  const int t = threadIdx.x;
  const int lane = t & 63, wv = t >> 6;
  const long row = (long)blockIdx.x * 4 + wv;
  const f16x4 v = *reinterpret_cast<const f16x4*>(&logits16[row * ES_ + lane * 4]);
  float f0 = (float)v[0], f1 = (float)v[1], f2 = (float)v[2], f3 = (float)v[3];
  float mx = fmaxf(fmaxf(f0, f1), fmaxf(f2, f3));
#pragma unroll
  for (int o = 32; o; o >>= 1) mx = fmaxf(mx, __shfl_xor(mx, o));
  const float e0 = __expf(f0 - mx), e1 = __expf(f1 - mx);
  const float e2 = __expf(f2 - mx), e3 = __expf(f3 - mx);
  float sm = e0 + e1 + e2 + e3;
#pragma unroll
  for (int o = 32; o; o >>= 1) sm += __shfl_xor(sm, o);
  const float inv = 1.0f / sm;
  f16x4 r; r[0] = (f16)(e0 * inv); r[1] = (f16)(e1 * inv);
  r[2] = (f16)(e2 * inv); r[3] = (f16)(e3 * inv);
  *reinterpret_cast<f16x4*>(&comb16[row * ES_ + lane * 4]) = r;
}

// ===========================================================================
// Fused h->y kernel per (b,e): h = relu(slots @ w1T^T + b1) kept in LDS,
// then yT16[b][d][es] = (h @ w2T[a-slice]^T + b2 slice) transposed write.
// 512 threads = 8 waves.
// ===========================================================================
#define HPAD 520   // 512 + 8 f16 pad: even bank spread for b128 reads

__global__ __launch_bounds__(512) void k_hy(
    const f16* __restrict__ slots16, const f16* __restrict__ w1T,
    const float* __restrict__ b1, const f16* __restrict__ w2T,
    const float* __restrict__ b2, const int* __restrict__ action,
    f16* __restrict__ yT16)
{
  __shared__ f16 hs[64][HPAD];
  const int z = blockIdx.x;
  const int b = z >> 2, e = z & 3;
  int a = action[b];
  a = (a < 0) ? 0 : (a >= A_ ? A_ - 1 : a);

  const int t = threadIdx.x, w = t >> 6, lane = t & 63;
  const int lr = lane & 15, lk = (lane >> 4) * 8;
  const int orow = (lane >> 4) * 4;

  // ---- GEMM1: h[64][512] = relu(slots[64x256] @ w1T[e][512x256]^T + b1) ---
  {
    const int n0 = w * 64;                 // wave covers h-cols n0..n0+63
    f32x4 acc[4][4] = {};
    const f16* Ap = slots16 + (long)z * (S_ * D_) + (long)lr * D_ + lk;
    const f16* Bp = w1T + (long)e * (H_ * D_) + (long)(n0 + lr) * D_ + lk;
#pragma unroll
    for (int k0 = 0; k0 < D_; k0 += 32) {
      f16x8 af[4], bf[4];
#pragma unroll
      for (int fi = 0; fi < 4; ++fi)
        af[fi] = *reinterpret_cast<const f16x8*>(Ap + (long)fi * 16 * D_ + k0);
#pragma unroll
      for (int fj = 0; fj < 4; ++fj)
        bf[fj] = *reinterpret_cast<const f16x8*>(Bp + (long)fj * 16 * D_ + k0);
#pragma unroll
      for (int fi = 0; fi < 4; ++fi)
#pragma unroll
        for (int fj = 0; fj < 4; ++fj)
          acc[fi][fj] = __builtin_amdgcn_mfma_f32_16x16x32_f16(
              af[fi], bf[fj], acc[fi][fj], 0, 0, 0);
    }
#pragma unroll
    for (int fi = 0; fi < 4; ++fi)
#pragma unroll
      for (int fj = 0; fj < 4; ++fj) {
        const int gm = fi * 16 + orow;
        const int gn = n0 + fj * 16 + lr;
        const float bv = b1[e * H_ + gn];
#pragma unroll
        for (int r = 0; r < 4; ++r)
          hs[gm + r][gn] = (f16)fmaxf(acc[fi][fj][r] + bv, 0.f);
      }
  }
  __syncthreads();

  // ---- GEMM2: y[64 s][256 d] = h @ w2T[e][a*D..][512]^T + b2 slice --------
  {
    const int wr2 = w >> 2, wc2 = w & 3;   // 2x4 wave grid
    const int m0 = wr2 * 32, n0 = wc2 * 64;
    f32x4 acc[2][4] = {};
    const f16* Bp = w2T + (long)e * ((long)K2_ * H_)
                  + ((long)a * D_ + n0 + lr) * H_ + lk;
#pragma unroll 4
    for (int k0 = 0; k0 < H_; k0 += 32) {
      f16x8 af[2], bf[4];
#pragma unroll
      for (int fi = 0; fi < 2; ++fi)
        af[fi] = *reinterpret_cast<const f16x8*>(&hs[m0 + fi * 16 + lr][k0 + lk]);
#pragma unroll
      for (int fj = 0; fj < 4; ++fj)
        bf[fj] = *reinterpret_cast<const f16x8*>(Bp + (long)fj * 16 * H_ + k0);
#pragma unroll
      for (int fi = 0; fi < 2; ++fi)
#pragma unroll
        for (int fj = 0; fj < 4; ++fj)
          acc[fi][fj] = __builtin_amdgcn_mfma_f32_16x16x32_f16(
              af[fi], bf[fj], acc[fi][fj], 0, 0, 0);
    }
    // transposed write: yT16[b][d = gn][es = e*64 + gm .. +3]
#pragma unroll
    for (int fi = 0; fi < 2; ++fi)
#pragma unroll
      for (int fj = 0; fj < 4; ++fj) {
        const int gm = m0 + fi * 16 + orow;      // s
        const int gn = n0 + fj * 16 + lr;        // d
        const float bv = b2[e * K2_ + a * D_ + gn];
        f16x4 h4;
#pragma unroll
        for (int r = 0; r < 4; ++r) h4[r] = (f16)(acc[fi][fj][r] + bv);
        *reinterpret_cast<f16x4*>(
            &yT16[(long)b * (D_ * ES_) + (long)gn * ES_ + e * S_ + gm]) = h4;
      }
  }
}

// ===========================================================================
extern "C" void kernel_launch(void* const* d_in, const int* in_sizes, int n_in,
                              void* d_out, int out_size, void* d_ws, size_t ws_size,
                              hipStream_t stream)
{
  const float* obs    = (const float*)d_in[0];
  const int*   action = (const int*)d_in[1];
  const float* phi    = (const float*)d_in[2];
  const float* w1     = (const float*)d_in[3];
  const float* b1     = (const float*)d_in[4];
  const float* w2     = (const float*)d_in[5];
  const float* b2     = (const float*)d_in[6];
  float*       out    = (float*)d_out;

  // Workspace layout (f16 units, no aliasing, ~79 MB total)
  f16* ws = (f16*)d_ws;
  f16* obs16    = ws + 0;
  f16* obsT16   = ws + 4194304;
  f16* phiT     = ws + 8388608;
  f16* w1T      = ws + 8454144;
  f16* w2T      = ws + 8978432;
  f16* logits16 = ws + 18415616;
  f16* dispT16  = ws + 22609920;
  f16* comb16   = ws + 26804224;
  f16* slots16  = ws + 30998528;
  f16* yT16     = ws + 35192832;

  // --- one-time conversions ---
  k_cvt_obs<<<dim3(4, 4, 64), 256, 0, stream>>>(obs, obs16, obsT16);
  k_tcvt   <<<dim3(4, 4, 1),  256, 0, stream>>>(phi, phiT, 256, 256, 0, 0);
  k_tcvt   <<<dim3(8, 4, 4),  256, 0, stream>>>(w1, w1T, D_, H_,
                                                (long)D_ * H_, (long)H_ * D_);
  k_tcvt   <<<dim3(72, 8, 4), 256, 0, stream>>>(w2, w2T, H_, K2_,
                                                (long)H_ * K2_, (long)K2_ * H_);
  // --- pipeline ---
  k_logits   <<<dim3(4, 4, 64), 256, 0, stream>>>(obs16, phiT, logits16);
  k_dispatchT<<<dim3(4, 64),    256, 0, stream>>>(logits16, dispT16);
  k_combine  <<<dim3(4096),     256, 0, stream>>>(logits16, comb16);
  k_slots    <<<dim3(4, 4, 64), 256, 0, stream>>>(dispT16, obsT16, slots16);
  k_hy       <<<dim3(256),      512, 0, stream>>>(slots16, w1T, b1, w2T, b2,
                                                  action, yT16);
  k_out      <<<dim3(4, 4, 64), 256, 0, stream>>>(comb16, yT16, out);
}